// Round 1
// baseline (1916.998 us; speedup 1.0000x reference)
//
#include <hip/hip_runtime.h>

constexpr int N_NODES = 100000;
constexpr int N_EDGES = 1600000;
constexpr int IN_DIM  = 128;
constexpr int HID     = 64;
constexpr int C2      = 8;
constexpr int GDIM    = 24;
constexpr int NG      = 64;
constexpr float SLOPE = 0.01f;

__device__ __forceinline__ float lrelu(float v) { return v > 0.f ? v : SLOPE * v; }

// ---- degree (in-degree by dst; +1 self loop applied in k_dinv) ----
__global__ void k_deg(const int* __restrict__ dst, int* __restrict__ deg) {
    int e = blockIdx.x * blockDim.x + threadIdx.x;
    if (e < N_EDGES) atomicAdd(&deg[dst[e]], 1);
}

__global__ void k_dinv(const int* __restrict__ deg, float* __restrict__ dinv) {
    int i = blockIdx.x * blockDim.x + threadIdx.x;
    if (i < N_NODES) dinv[i] = rsqrtf((float)(deg[i] + 1));
}

// ---- layer-1 GEMM: hs1[n,:] = (x[n,:] @ W1) * dinv[n]   (128 -> 64) ----
__global__ __launch_bounds__(256) void k_gemm1(const float* __restrict__ x,
                                               const float* __restrict__ W1,
                                               const float* __restrict__ dinv,
                                               float* __restrict__ hs1) {
    __shared__ float sW[IN_DIM * HID];   // 32 KiB
    __shared__ float sX[4][IN_DIM];      // 2 KiB
    int node0 = blockIdx.x * 4;
    for (int i = threadIdx.x; i < IN_DIM * HID; i += 256) sW[i] = W1[i];
    for (int i = threadIdx.x; i < 4 * IN_DIM; i += 256) {
        int r = i / IN_DIM, k = i % IN_DIM;
        int n = node0 + r;
        sX[r][k] = (n < N_NODES) ? x[(long long)n * IN_DIM + k] : 0.f;
    }
    __syncthreads();
    int col  = threadIdx.x & 63;
    int sub  = threadIdx.x >> 6;
    int node = node0 + sub;
    if (node >= N_NODES) return;
    float acc = 0.f;
#pragma unroll 8
    for (int k = 0; k < IN_DIM; ++k) acc += sX[sub][k] * sW[k * HID + col];
    hs1[(long long)node * HID + col] = acc * dinv[node];
}

// ---- layer-1 scatter: agg1[dst,:] += hs1[src,:]  (16 threads/edge, float4) ----
__global__ void k_scatter1(const int* __restrict__ src, const int* __restrict__ dst,
                           const float* __restrict__ hs1, float* __restrict__ agg1) {
    long long t = (long long)blockIdx.x * blockDim.x + threadIdx.x;
    if (t >= (long long)N_EDGES * 16) return;
    int e = (int)(t >> 4);
    int q = (int)(t & 15);
    int s = src[e], d = dst[e];
    float4 v = ((const float4*)(hs1 + (long long)s * HID))[q];
    float* base = agg1 + (long long)d * HID + q * 4;
    atomicAdd(base + 0, v.x);
    atomicAdd(base + 1, v.y);
    atomicAdd(base + 2, v.z);
    atomicAdd(base + 3, v.w);
}

// ---- layer-1 epilogue: y1 = leaky(dinv*(agg1+hs1)+b1), written in-place into agg1 ----
__global__ void k_y1(float* __restrict__ agg1, const float* __restrict__ hs1,
                     const float* __restrict__ dinv, const float* __restrict__ b1) {
    int t = blockIdx.x * blockDim.x + threadIdx.x;
    constexpr int TOT = N_NODES * (HID / 4);
    if (t >= TOT) return;
    int node = t / (HID / 4);
    int c4   = t % (HID / 4);
    float di = dinv[node];
    float4 a = ((const float4*)agg1)[t];
    float4 h = ((const float4*)hs1)[t];
    const float* bb = b1 + c4 * 4;
    float4 r;
    r.x = lrelu(di * (a.x + h.x) + bb[0]);
    r.y = lrelu(di * (a.y + h.y) + bb[1]);
    r.z = lrelu(di * (a.z + h.z) + bb[2]);
    r.w = lrelu(di * (a.w + h.w) + bb[3]);
    ((float4*)agg1)[t] = r;
}

// ---- layer-2 GEMM: hs2[n,:] = (y1[n,:] @ W2) * dinv[n]   (64 -> 8) ----
__global__ __launch_bounds__(256) void k_gemm2(const float* __restrict__ y1,
                                               const float* __restrict__ W2,
                                               const float* __restrict__ dinv,
                                               float* __restrict__ hs2) {
    __shared__ float sW[HID * C2];       // 2 KiB
    __shared__ float sY[32][HID + 1];    // padded: avoid same-bank stride-64
    int node0 = blockIdx.x * 32;
    for (int i = threadIdx.x; i < HID * C2; i += 256) sW[i] = W2[i];
    for (int i = threadIdx.x; i < 32 * HID; i += 256) {
        int r = i / HID, k = i % HID;
        int n = node0 + r;
        sY[r][k] = (n < N_NODES) ? y1[(long long)n * HID + k] : 0.f;
    }
    __syncthreads();
    int col  = threadIdx.x & 7;
    int r    = threadIdx.x >> 3;
    int node = node0 + r;
    if (node >= N_NODES) return;
    float acc = 0.f;
#pragma unroll 8
    for (int k = 0; k < HID; ++k) acc += sY[r][k] * sW[k * C2 + col];
    hs2[(long long)node * C2 + col] = acc * dinv[node];
}

// ---- layer-2 scatter: agg2[dst,:] += hs2[src,:]  (2 threads/edge, float4) ----
__global__ void k_scatter2(const int* __restrict__ src, const int* __restrict__ dst,
                           const float* __restrict__ hs2, float* __restrict__ agg2) {
    long long t = (long long)blockIdx.x * blockDim.x + threadIdx.x;
    if (t >= (long long)N_EDGES * 2) return;
    int e = (int)(t >> 1);
    int q = (int)(t & 1);
    int s = src[e], d = dst[e];
    float4 v = ((const float4*)(hs2 + (long long)s * C2))[q];
    float* base = agg2 + (long long)d * C2 + q * 4;
    atomicAdd(base + 0, v.x);
    atomicAdd(base + 1, v.y);
    atomicAdd(base + 2, v.z);
    atomicAdd(base + 3, v.w);
}

// ---- layer-2 epilogue fused with mean-pool partial sums ----
__global__ __launch_bounds__(256) void k_pool(const float* __restrict__ agg2,
                                              const float* __restrict__ hs2,
                                              const float* __restrict__ dinv,
                                              const float* __restrict__ b2,
                                              const int* __restrict__ batch,
                                              float* __restrict__ gsum,
                                              float* __restrict__ gcnt) {
    __shared__ float ssum[NG * C2];
    __shared__ float scnt[NG];
    for (int i = threadIdx.x; i < NG * C2; i += 256) ssum[i] = 0.f;
    for (int i = threadIdx.x; i < NG; i += 256) scnt[i] = 0.f;
    __syncthreads();
    int node = blockIdx.x * 32 + (threadIdx.x >> 3);
    int col  = threadIdx.x & 7;
    if (node < N_NODES) {
        int g = batch[node];
        long long idx = (long long)node * C2 + col;
        float v = lrelu(dinv[node] * (agg2[idx] + hs2[idx]) + b2[col]);
        atomicAdd(&ssum[g * C2 + col], v);
        if (col == 0) atomicAdd(&scnt[g], 1.f);
    }
    __syncthreads();
    for (int i = threadIdx.x; i < NG * C2; i += 256)
        if (ssum[i] != 0.f) atomicAdd(&gsum[i], ssum[i]);
    for (int i = threadIdx.x; i < NG; i += 256)
        if (scnt[i] != 0.f) atomicAdd(&gcnt[i], scnt[i]);
}

// ---- final MLP: one thread per graph ----
__global__ void k_mlp(const float* __restrict__ gsum, const float* __restrict__ gcnt,
                      const float* __restrict__ gfeat,
                      const float* __restrict__ fcW1, const float* __restrict__ fcb1,
                      const float* __restrict__ fcW2, const float* __restrict__ fcb2,
                      float* __restrict__ out) {
    int g = threadIdx.x;
    if (g >= NG) return;
    float z[C2 + GDIM];
    float cnt = fmaxf(gcnt[g], 1.f);
    for (int c = 0; c < C2; ++c) z[c] = gsum[g * C2 + c] / cnt;
    for (int c = 0; c < GDIM; ++c) z[C2 + c] = gfeat[g * GDIM + c];
    float h16[16];
    for (int j = 0; j < 16; ++j) {
        float acc = fcb1[j];
        for (int c = 0; c < C2 + GDIM; ++c) acc += z[c] * fcW1[c * 16 + j];
        h16[j] = lrelu(acc);
    }
    float acc = fcb2[0];
    for (int j = 0; j < 16; ++j) acc += h16[j] * fcW2[j];
    out[g] = lrelu(acc);
}

extern "C" void kernel_launch(void* const* d_in, const int* in_sizes, int n_in,
                              void* d_out, int out_size, void* d_ws, size_t ws_size,
                              hipStream_t stream) {
    const float* x     = (const float*)d_in[0];
    const int*   ei    = (const int*)d_in[1];
    const int*   batch = (const int*)d_in[2];
    const float* gfeat = (const float*)d_in[3];
    const float* W1    = (const float*)d_in[4];
    const float* b1    = (const float*)d_in[5];
    const float* W2    = (const float*)d_in[6];
    const float* b2    = (const float*)d_in[7];
    const float* fcW1  = (const float*)d_in[8];
    const float* fcb1  = (const float*)d_in[9];
    const float* fcW2  = (const float*)d_in[10];
    const float* fcb2  = (const float*)d_in[11];
    const int* src = ei;
    const int* dst = ei + N_EDGES;

    char* ws = (char*)d_ws;
    size_t off = 0;
    auto alloc = [&](size_t bytes) -> void* {
        void* p = ws + off;
        off = (off + bytes + 255) & ~(size_t)255;
        return p;
    };
    int*   deg  = (int*)  alloc((size_t)N_NODES * 4);
    float* dinv = (float*)alloc((size_t)N_NODES * 4);
    float* hs1  = (float*)alloc((size_t)N_NODES * HID * 4);
    float* agg1 = (float*)alloc((size_t)N_NODES * HID * 4);
    float* hs2  = (float*)alloc((size_t)N_NODES * C2 * 4);
    float* agg2 = (float*)alloc((size_t)N_NODES * C2 * 4);
    float* gsum = (float*)alloc((size_t)NG * C2 * 4);
    float* gcnt = (float*)alloc((size_t)NG * 4);

    hipMemsetAsync(deg,  0, (size_t)N_NODES * 4, stream);
    hipMemsetAsync(agg1, 0, (size_t)N_NODES * HID * 4, stream);
    hipMemsetAsync(agg2, 0, (size_t)N_NODES * C2 * 4, stream);
    hipMemsetAsync(gsum, 0, (size_t)NG * C2 * 4, stream);
    hipMemsetAsync(gcnt, 0, (size_t)NG * 4, stream);

    k_deg <<<(N_EDGES + 255) / 256, 256, 0, stream>>>(dst, deg);
    k_dinv<<<(N_NODES + 255) / 256, 256, 0, stream>>>(deg, dinv);
    k_gemm1<<<(N_NODES + 3) / 4, 256, 0, stream>>>(x, W1, dinv, hs1);
    k_scatter1<<<(int)(((long long)N_EDGES * 16 + 255) / 256), 256, 0, stream>>>(src, dst, hs1, agg1);
    k_y1<<<(N_NODES * (HID / 4) + 255) / 256, 256, 0, stream>>>(agg1, hs1, dinv, b1);
    k_gemm2<<<(N_NODES + 31) / 32, 256, 0, stream>>>(agg1, W2, dinv, hs2);
    k_scatter2<<<(int)(((long long)N_EDGES * 2 + 255) / 256), 256, 0, stream>>>(src, dst, hs2, agg2);
    k_pool<<<(N_NODES + 31) / 32, 256, 0, stream>>>(agg2, hs2, dinv, b2, batch, gsum, gcnt);
    k_mlp<<<1, 64, 0, stream>>>(gsum, gcnt, gfeat, fcW1, fcb1, fcW2, fcb2, (float*)d_out);
}

// Round 2
// 453.443 us; speedup vs baseline: 4.2276x; 4.2276x over previous
//
#include <hip/hip_runtime.h>

constexpr int N_NODES = 100000;
constexpr int N_EDGES = 1600000;
constexpr int IN_DIM  = 128;
constexpr int HID     = 64;
constexpr int C2      = 8;
constexpr int GDIM    = 24;
constexpr int NG      = 64;
constexpr float SLOPE = 0.01f;
constexpr int NB_SCAN = (N_NODES + 255) / 256;   // 391 scan blocks

__device__ __forceinline__ float lrelu(float v) { return v > 0.f ? v : SLOPE * v; }

// ---- degree (in-degree by dst; +1 self loop applied in k_dinv) ----
__global__ void k_deg(const int* __restrict__ dst, int* __restrict__ deg) {
    int e = blockIdx.x * blockDim.x + threadIdx.x;
    if (e < N_EDGES) atomicAdd(&deg[dst[e]], 1);
}

__global__ void k_dinv(const int* __restrict__ deg, float* __restrict__ dinv) {
    int i = blockIdx.x * blockDim.x + threadIdx.x;
    if (i < N_NODES) dinv[i] = rsqrtf((float)(deg[i] + 1));
}

// ---- exclusive scan of deg -> rowptr (3-kernel hierarchical scan) ----
__global__ void k_scan1(const int* __restrict__ deg, int* __restrict__ rowptr,
                        int* __restrict__ bsum) {
    __shared__ int s[256];
    int tid = threadIdx.x;
    int i = blockIdx.x * 256 + tid;
    int v = (i < N_NODES) ? deg[i] : 0;
    s[tid] = v;
    __syncthreads();
    for (int off = 1; off < 256; off <<= 1) {
        int t = (tid >= off) ? s[tid - off] : 0;
        __syncthreads();
        s[tid] += t;
        __syncthreads();
    }
    if (i < N_NODES) rowptr[i] = s[tid] - v;          // exclusive, block-local
    if (tid == 255) bsum[blockIdx.x] = s[255];
}

__global__ void k_scan2(const int* __restrict__ bsum, int* __restrict__ bsumx) {
    __shared__ int s[512];
    int tid = threadIdx.x;
    int v = (tid < NB_SCAN) ? bsum[tid] : 0;
    s[tid] = v;
    __syncthreads();
    for (int off = 1; off < 512; off <<= 1) {
        int t = (tid >= off) ? s[tid - off] : 0;
        __syncthreads();
        s[tid] += t;
        __syncthreads();
    }
    if (tid < NB_SCAN) bsumx[tid] = s[tid] - v;        // exclusive
}

__global__ void k_scan3(int* __restrict__ rowptr, const int* __restrict__ bsumx,
                        int* __restrict__ cursor) {
    int i = blockIdx.x * 256 + threadIdx.x;
    if (i < N_NODES) {
        int r = rowptr[i] + bsumx[blockIdx.x];
        rowptr[i] = r;
        cursor[i] = r;
    }
}

// ---- bucket fill: eidx[bucket(dst)] = src ----
__global__ void k_fill(const int* __restrict__ src, const int* __restrict__ dst,
                       int* __restrict__ cursor, int* __restrict__ eidx) {
    int e = blockIdx.x * blockDim.x + threadIdx.x;
    if (e < N_EDGES) {
        int pos = atomicAdd(&cursor[dst[e]], 1);
        eidx[pos] = src[e];
    }
}

// ---- layer-1 GEMM: hs1[n,:] = (x[n,:] @ W1) * dinv[n]   (128 -> 64) ----
__global__ __launch_bounds__(256) void k_gemm1(const float* __restrict__ x,
                                               const float* __restrict__ W1,
                                               const float* __restrict__ dinv,
                                               float* __restrict__ hs1) {
    __shared__ float sW[IN_DIM * HID];   // 32 KiB
    __shared__ float sX[4][IN_DIM];      // 2 KiB
    int node0 = blockIdx.x * 4;
    for (int i = threadIdx.x; i < IN_DIM * HID; i += 256) sW[i] = W1[i];
    for (int i = threadIdx.x; i < 4 * IN_DIM; i += 256) {
        int r = i / IN_DIM, k = i % IN_DIM;
        int n = node0 + r;
        sX[r][k] = (n < N_NODES) ? x[(long long)n * IN_DIM + k] : 0.f;
    }
    __syncthreads();
    int col  = threadIdx.x & 63;
    int sub  = threadIdx.x >> 6;
    int node = node0 + sub;
    if (node >= N_NODES) return;
    float acc = 0.f;
#pragma unroll 8
    for (int k = 0; k < IN_DIM; ++k) acc += sX[sub][k] * sW[k * HID + col];
    hs1[(long long)node * HID + col] = acc * dinv[node];
}

// ---- layer-1 aggregate+epilogue: one wave per node ----
// lanes: slot = lane>>4 (4 edge slots), q = lane&15 (16 float4 columns)
__global__ __launch_bounds__(256) void k_agg1(const int* __restrict__ rowptr,
                                              const int* __restrict__ deg,
                                              const int* __restrict__ eidx,
                                              const float* __restrict__ hs1,
                                              const float* __restrict__ dinv,
                                              const float* __restrict__ b1,
                                              float* __restrict__ y1) {
    int node = blockIdx.x * 4 + (threadIdx.x >> 6);
    if (node >= N_NODES) return;
    int lane = threadIdx.x & 63;
    int q    = lane & 15;
    int slot = lane >> 4;
    int start = rowptr[node];
    int cnt   = deg[node];
    float4 acc = make_float4(0.f, 0.f, 0.f, 0.f);
    for (int k = slot; k < cnt; k += 4) {
        int s = eidx[start + k];
        float4 v = ((const float4*)(hs1 + (long long)s * HID))[q];
        acc.x += v.x; acc.y += v.y; acc.z += v.z; acc.w += v.w;
    }
    // reduce across the 4 slots (lane bits 4,5)
    acc.x += __shfl_xor(acc.x, 16); acc.y += __shfl_xor(acc.y, 16);
    acc.z += __shfl_xor(acc.z, 16); acc.w += __shfl_xor(acc.w, 16);
    acc.x += __shfl_xor(acc.x, 32); acc.y += __shfl_xor(acc.y, 32);
    acc.z += __shfl_xor(acc.z, 32); acc.w += __shfl_xor(acc.w, 32);
    if (slot == 0) {
        float4 h = ((const float4*)(hs1 + (long long)node * HID))[q];
        float di = dinv[node];
        const float* bb = b1 + q * 4;
        float4 r;
        r.x = lrelu(di * (acc.x + h.x) + bb[0]);
        r.y = lrelu(di * (acc.y + h.y) + bb[1]);
        r.z = lrelu(di * (acc.z + h.z) + bb[2]);
        r.w = lrelu(di * (acc.w + h.w) + bb[3]);
        ((float4*)(y1 + (long long)node * HID))[q] = r;
    }
}

// ---- layer-2 GEMM: hs2[n,:] = (y1[n,:] @ W2) * dinv[n]   (64 -> 8) ----
__global__ __launch_bounds__(256) void k_gemm2(const float* __restrict__ y1,
                                               const float* __restrict__ W2,
                                               const float* __restrict__ dinv,
                                               float* __restrict__ hs2) {
    __shared__ float sW[HID * C2];       // 2 KiB
    __shared__ float sY[32][HID + 1];
    int node0 = blockIdx.x * 32;
    for (int i = threadIdx.x; i < HID * C2; i += 256) sW[i] = W2[i];
    for (int i = threadIdx.x; i < 32 * HID; i += 256) {
        int r = i / HID, k = i % HID;
        int n = node0 + r;
        sY[r][k] = (n < N_NODES) ? y1[(long long)n * HID + k] : 0.f;
    }
    __syncthreads();
    int col  = threadIdx.x & 7;
    int r    = threadIdx.x >> 3;
    int node = node0 + r;
    if (node >= N_NODES) return;
    float acc = 0.f;
#pragma unroll 8
    for (int k = 0; k < HID; ++k) acc += sY[r][k] * sW[k * C2 + col];
    hs2[(long long)node * C2 + col] = acc * dinv[node];
}

// ---- layer-2 aggregate+epilogue: one wave per node ----
// lanes: q = lane&1 (2 float4 columns), slot = lane>>1 (32 edge slots)
__global__ __launch_bounds__(256) void k_agg2(const int* __restrict__ rowptr,
                                              const int* __restrict__ deg,
                                              const int* __restrict__ eidx,
                                              const float* __restrict__ hs2,
                                              const float* __restrict__ dinv,
                                              const float* __restrict__ b2,
                                              float* __restrict__ y2) {
    int node = blockIdx.x * 4 + (threadIdx.x >> 6);
    if (node >= N_NODES) return;
    int lane = threadIdx.x & 63;
    int q    = lane & 1;
    int slot = lane >> 1;
    int start = rowptr[node];
    int cnt   = deg[node];
    float4 acc = make_float4(0.f, 0.f, 0.f, 0.f);
    for (int k = slot; k < cnt; k += 32) {
        int s = eidx[start + k];
        float4 v = ((const float4*)(hs2 + (long long)s * C2))[q];
        acc.x += v.x; acc.y += v.y; acc.z += v.z; acc.w += v.w;
    }
    // reduce across 32 slots (lane bits 1..5)
    for (int m = 2; m < 64; m <<= 1) {
        acc.x += __shfl_xor(acc.x, m); acc.y += __shfl_xor(acc.y, m);
        acc.z += __shfl_xor(acc.z, m); acc.w += __shfl_xor(acc.w, m);
    }
    if (slot == 0) {
        float4 h = ((const float4*)(hs2 + (long long)node * C2))[q];
        float di = dinv[node];
        const float* bb = b2 + q * 4;
        float4 r;
        r.x = lrelu(di * (acc.x + h.x) + bb[0]);
        r.y = lrelu(di * (acc.y + h.y) + bb[1]);
        r.z = lrelu(di * (acc.z + h.z) + bb[2]);
        r.w = lrelu(di * (acc.w + h.w) + bb[3]);
        ((float4*)(y2 + (long long)node * C2))[q] = r;
    }
}

// ---- mean-pool partial sums ----
__global__ __launch_bounds__(256) void k_pool(const float* __restrict__ y2,
                                              const int* __restrict__ batch,
                                              float* __restrict__ gsum,
                                              float* __restrict__ gcnt) {
    __shared__ float ssum[NG * C2];
    __shared__ float scnt[NG];
    for (int i = threadIdx.x; i < NG * C2; i += 256) ssum[i] = 0.f;
    for (int i = threadIdx.x; i < NG; i += 256) scnt[i] = 0.f;
    __syncthreads();
    int node = blockIdx.x * 32 + (threadIdx.x >> 3);
    int col  = threadIdx.x & 7;
    if (node < N_NODES) {
        int g = batch[node];
        float v = y2[(long long)node * C2 + col];
        atomicAdd(&ssum[g * C2 + col], v);
        if (col == 0) atomicAdd(&scnt[g], 1.f);
    }
    __syncthreads();
    for (int i = threadIdx.x; i < NG * C2; i += 256)
        if (ssum[i] != 0.f) atomicAdd(&gsum[i], ssum[i]);
    for (int i = threadIdx.x; i < NG; i += 256)
        if (scnt[i] != 0.f) atomicAdd(&gcnt[i], scnt[i]);
}

// ---- final MLP: one thread per graph ----
__global__ void k_mlp(const float* __restrict__ gsum, const float* __restrict__ gcnt,
                      const float* __restrict__ gfeat,
                      const float* __restrict__ fcW1, const float* __restrict__ fcb1,
                      const float* __restrict__ fcW2, const float* __restrict__ fcb2,
                      float* __restrict__ out) {
    int g = threadIdx.x;
    if (g >= NG) return;
    float z[C2 + GDIM];
    float cnt = fmaxf(gcnt[g], 1.f);
    for (int c = 0; c < C2; ++c) z[c] = gsum[g * C2 + c] / cnt;
    for (int c = 0; c < GDIM; ++c) z[C2 + c] = gfeat[g * GDIM + c];
    float h16[16];
    for (int j = 0; j < 16; ++j) {
        float acc = fcb1[j];
        for (int c = 0; c < C2 + GDIM; ++c) acc += z[c] * fcW1[c * 16 + j];
        h16[j] = lrelu(acc);
    }
    float acc = fcb2[0];
    for (int j = 0; j < 16; ++j) acc += h16[j] * fcW2[j];
    out[g] = lrelu(acc);
}

extern "C" void kernel_launch(void* const* d_in, const int* in_sizes, int n_in,
                              void* d_out, int out_size, void* d_ws, size_t ws_size,
                              hipStream_t stream) {
    const float* x     = (const float*)d_in[0];
    const int*   ei    = (const int*)d_in[1];
    const int*   batch = (const int*)d_in[2];
    const float* gfeat = (const float*)d_in[3];
    const float* W1    = (const float*)d_in[4];
    const float* b1    = (const float*)d_in[5];
    const float* W2    = (const float*)d_in[6];
    const float* b2    = (const float*)d_in[7];
    const float* fcW1  = (const float*)d_in[8];
    const float* fcb1  = (const float*)d_in[9];
    const float* fcW2  = (const float*)d_in[10];
    const float* fcb2  = (const float*)d_in[11];
    const int* src = ei;
    const int* dst = ei + N_EDGES;

    char* ws = (char*)d_ws;
    size_t off = 0;
    auto alloc = [&](size_t bytes) -> void* {
        void* p = ws + off;
        off = (off + bytes + 255) & ~(size_t)255;
        return p;
    };
    int*   deg    = (int*)  alloc((size_t)N_NODES * 4);
    float* dinv   = (float*)alloc((size_t)N_NODES * 4);
    int*   rowptr = (int*)  alloc((size_t)N_NODES * 4);
    int*   cursor = (int*)  alloc((size_t)N_NODES * 4);
    int*   bsum   = (int*)  alloc(512 * 4);
    int*   bsumx  = (int*)  alloc(512 * 4);
    int*   eidx   = (int*)  alloc((size_t)N_EDGES * 4);
    float* hs1    = (float*)alloc((size_t)N_NODES * HID * 4);
    float* y1     = (float*)alloc((size_t)N_NODES * HID * 4);
    float* gsum   = (float*)alloc((size_t)NG * C2 * 4);
    float* gcnt   = (float*)alloc((size_t)NG * 4);
    // hs2/y2 alias the (dead-after-agg1) hs1 region
    float* hs2 = hs1;
    float* y2  = hs1 + (size_t)N_NODES * (HID / 2);

    hipMemsetAsync(deg,  0, (size_t)N_NODES * 4, stream);
    hipMemsetAsync(gsum, 0, (size_t)NG * C2 * 4, stream);
    hipMemsetAsync(gcnt, 0, (size_t)NG * 4, stream);

    k_deg  <<<(N_EDGES + 255) / 256, 256, 0, stream>>>(dst, deg);
    k_dinv <<<(N_NODES + 255) / 256, 256, 0, stream>>>(deg, dinv);
    k_scan1<<<NB_SCAN, 256, 0, stream>>>(deg, rowptr, bsum);
    k_scan2<<<1, 512, 0, stream>>>(bsum, bsumx);
    k_scan3<<<NB_SCAN, 256, 0, stream>>>(rowptr, bsumx, cursor);
    k_fill <<<(N_EDGES + 255) / 256, 256, 0, stream>>>(src, dst, cursor, eidx);

    k_gemm1<<<(N_NODES + 3) / 4, 256, 0, stream>>>(x, W1, dinv, hs1);
    k_agg1 <<<(N_NODES + 3) / 4, 256, 0, stream>>>(rowptr, deg, eidx, hs1, dinv, b1, y1);
    k_gemm2<<<(N_NODES + 31) / 32, 256, 0, stream>>>(y1, W2, dinv, hs2);
    k_agg2 <<<(N_NODES + 3) / 4, 256, 0, stream>>>(rowptr, deg, eidx, hs2, dinv, b2, y2);
    k_pool <<<(N_NODES + 31) / 32, 256, 0, stream>>>(y2, batch, gsum, gcnt);
    k_mlp  <<<1, 64, 0, stream>>>(gsum, gcnt, gfeat, fcW1, fcb1, fcW2, fcb2, (float*)d_out);
}

// Round 3
// 289.045 us; speedup vs baseline: 6.6322x; 1.5688x over previous
//
#include <hip/hip_runtime.h>

constexpr int N_NODES = 100000;
constexpr int N_EDGES = 1600000;
constexpr int IN_DIM  = 128;
constexpr int HID     = 64;
constexpr int C2      = 8;
constexpr int GDIM    = 24;
constexpr int NG      = 64;
constexpr float SLOPE = 0.01f;
constexpr int NB_SCAN = (N_NODES + 255) / 256;   // 391

__device__ __forceinline__ float lrelu(float v) { return v > 0.f ? v : SLOPE * v; }

// ---- rank pass: deg histogram + per-edge rank in one pass ----
__global__ void k_rank(const int* __restrict__ dst, int* __restrict__ deg,
                       int* __restrict__ rnk) {
    int e = blockIdx.x * 256 + threadIdx.x;
    if (e < N_EDGES) rnk[e] = atomicAdd(&deg[dst[e]], 1);
}

// ---- dinv + zero the pool accumulators (saves two memsets) ----
__global__ void k_dinv(const int* __restrict__ deg, float* __restrict__ dinv,
                       float* __restrict__ gacc) {
    int i = blockIdx.x * 256 + threadIdx.x;
    if (i < N_NODES) dinv[i] = rsqrtf((float)(deg[i] + 1));
    if (blockIdx.x == 0)
        for (int j = threadIdx.x; j < NG * C2 + NG; j += 256) gacc[j] = 0.f;
}

// ---- exclusive scan of deg -> rowptr ----
__global__ void k_scan1(const int* __restrict__ deg, int* __restrict__ rowptr,
                        int* __restrict__ bsum) {
    __shared__ int s[256];
    int tid = threadIdx.x;
    int i = blockIdx.x * 256 + tid;
    int v = (i < N_NODES) ? deg[i] : 0;
    s[tid] = v;
    __syncthreads();
    for (int off = 1; off < 256; off <<= 1) {
        int t = (tid >= off) ? s[tid - off] : 0;
        __syncthreads();
        s[tid] += t;
        __syncthreads();
    }
    if (i < N_NODES) rowptr[i] = s[tid] - v;
    if (tid == 255) bsum[blockIdx.x] = s[255];
}

__global__ void k_scan2(const int* __restrict__ bsum, int* __restrict__ bsumx) {
    __shared__ int s[512];
    int tid = threadIdx.x;
    int v = (tid < NB_SCAN) ? bsum[tid] : 0;
    s[tid] = v;
    __syncthreads();
    for (int off = 1; off < 512; off <<= 1) {
        int t = (tid >= off) ? s[tid - off] : 0;
        __syncthreads();
        s[tid] += t;
        __syncthreads();
    }
    if (tid < NB_SCAN) bsumx[tid] = s[tid] - v;
}

__global__ void k_scan3(int* __restrict__ rowptr, const int* __restrict__ bsumx) {
    int i = blockIdx.x * 256 + threadIdx.x;
    if (i < N_NODES) rowptr[i] += bsumx[blockIdx.x];
}

// ---- place: atomic-free scatter using precomputed ranks ----
__global__ void k_place(const int* __restrict__ src, const int* __restrict__ dst,
                        const int* __restrict__ rnk, const int* __restrict__ rowptr,
                        int* __restrict__ eidx) {
    int e = blockIdx.x * 256 + threadIdx.x;
    if (e < N_EDGES) eidx[rowptr[dst[e]] + rnk[e]] = src[e];
}

// ---- layer-1 GEMM: 32 nodes/block, wave handles 8 nodes ----
__global__ __launch_bounds__(256) void k_gemm1(const float* __restrict__ x,
                                               const float* __restrict__ W1,
                                               const float* __restrict__ dinv,
                                               float* __restrict__ hs1) {
    __shared__ float sW[IN_DIM * HID];   // 32 KiB
    __shared__ float sX[32][IN_DIM];     // 16 KiB
    int node0 = blockIdx.x * 32;         // 3125 blocks * 32 == 100000 exactly
    for (int t = threadIdx.x; t < IN_DIM * HID / 4; t += 256)
        ((float4*)sW)[t] = ((const float4*)W1)[t];
    for (int t = threadIdx.x; t < 32 * IN_DIM / 4; t += 256) {
        int r = t >> 5, c4 = t & 31;
        ((float4*)&sX[r][0])[c4] = ((const float4*)(x + (size_t)(node0 + r) * IN_DIM))[c4];
    }
    __syncthreads();
    int col = threadIdx.x & 63;
    int nb  = (threadIdx.x >> 6) * 8;    // local node base for this wave
    float acc[8] = {0.f, 0.f, 0.f, 0.f, 0.f, 0.f, 0.f, 0.f};
#pragma unroll 4
    for (int k = 0; k < IN_DIM; ++k) {
        float wv = sW[k * HID + col];
#pragma unroll
        for (int j = 0; j < 8; ++j) acc[j] += sX[nb + j][k] * wv;
    }
#pragma unroll
    for (int j = 0; j < 8; ++j) {
        int n = node0 + nb + j;
        hs1[(size_t)n * HID + col] = acc[j] * dinv[n];
    }
}

// ---- layer-1 aggregate + epilogue + FUSED layer-2 GEMM ----
// wave per node; q = lane&15 (16 float4 cols), slot = lane>>4 (4 edge slots)
__global__ __launch_bounds__(256) void k_agg1(const int* __restrict__ rowptr,
                                              const int* __restrict__ deg,
                                              const int* __restrict__ eidx,
                                              const float* __restrict__ hs1,
                                              const float* __restrict__ dinv,
                                              const float* __restrict__ b1,
                                              const float* __restrict__ W2,
                                              float* __restrict__ hs2) {
    __shared__ float sW2t[C2 * HID];     // transposed: [j][k]
    for (int i = threadIdx.x; i < HID * C2; i += 256) {
        int k = i >> 3, j = i & 7;
        sW2t[j * HID + k] = W2[i];
    }
    __syncthreads();
    int node = blockIdx.x * 4 + (threadIdx.x >> 6);   // 25000 blocks * 4 == 100000
    int lane = threadIdx.x & 63;
    int q    = lane & 15;
    int slot = lane >> 4;
    int start = rowptr[node];
    int cnt   = deg[node];
    float4 acc = make_float4(0.f, 0.f, 0.f, 0.f);
    for (int k = slot; k < cnt; k += 4) {
        int s = eidx[start + k];
        float4 v = ((const float4*)(hs1 + (size_t)s * HID))[q];
        acc.x += v.x; acc.y += v.y; acc.z += v.z; acc.w += v.w;
    }
    // butterfly across slots -> ALL lanes hold the full sum for their q
    acc.x += __shfl_xor(acc.x, 16); acc.y += __shfl_xor(acc.y, 16);
    acc.z += __shfl_xor(acc.z, 16); acc.w += __shfl_xor(acc.w, 16);
    acc.x += __shfl_xor(acc.x, 32); acc.y += __shfl_xor(acc.y, 32);
    acc.z += __shfl_xor(acc.z, 32); acc.w += __shfl_xor(acc.w, 32);
    float4 h  = ((const float4*)(hs1 + (size_t)node * HID))[q];
    float  di = dinv[node];
    float4 bb = ((const float4*)b1)[q];
    float4 y;
    y.x = lrelu(di * (acc.x + h.x) + bb.x);
    y.y = lrelu(di * (acc.y + h.y) + bb.y);
    y.z = lrelu(di * (acc.z + h.z) + bb.z);
    y.w = lrelu(di * (acc.w + h.w) + bb.w);
    // fused gemm2: slot s computes outputs j0=2s, j0+1
    int j0 = slot * 2;
    const float* w0 = sW2t + j0 * HID + 4 * q;
    const float* w1 = w0 + HID;
    float p0 = y.x * w0[0] + y.y * w0[1] + y.z * w0[2] + y.w * w0[3];
    float p1 = y.x * w1[0] + y.y * w1[1] + y.z * w1[2] + y.w * w1[3];
#pragma unroll
    for (int m = 1; m < 16; m <<= 1) {
        p0 += __shfl_xor(p0, m);
        p1 += __shfl_xor(p1, m);
    }
    if (q == 0) {
        float2 r; r.x = p0 * di; r.y = p1 * di;
        ((float2*)(hs2 + (size_t)node * C2))[slot] = r;
    }
}

// ---- layer-2 aggregate + epilogue ----
__global__ __launch_bounds__(256) void k_agg2(const int* __restrict__ rowptr,
                                              const int* __restrict__ deg,
                                              const int* __restrict__ eidx,
                                              const float* __restrict__ hs2,
                                              const float* __restrict__ dinv,
                                              const float* __restrict__ b2,
                                              float* __restrict__ y2) {
    int node = blockIdx.x * 4 + (threadIdx.x >> 6);
    int lane = threadIdx.x & 63;
    int q    = lane & 1;
    int slot = lane >> 1;
    int start = rowptr[node];
    int cnt   = deg[node];
    float4 acc = make_float4(0.f, 0.f, 0.f, 0.f);
    for (int k = slot; k < cnt; k += 32) {
        int s = eidx[start + k];
        float4 v = ((const float4*)(hs2 + (size_t)s * C2))[q];
        acc.x += v.x; acc.y += v.y; acc.z += v.z; acc.w += v.w;
    }
    for (int m = 2; m < 64; m <<= 1) {
        acc.x += __shfl_xor(acc.x, m); acc.y += __shfl_xor(acc.y, m);
        acc.z += __shfl_xor(acc.z, m); acc.w += __shfl_xor(acc.w, m);
    }
    if (slot == 0) {
        float4 h = ((const float4*)(hs2 + (size_t)node * C2))[q];
        float di = dinv[node];
        const float* bb = b2 + q * 4;
        float4 r;
        r.x = lrelu(di * (acc.x + h.x) + bb[0]);
        r.y = lrelu(di * (acc.y + h.y) + bb[1]);
        r.z = lrelu(di * (acc.z + h.z) + bb[2]);
        r.w = lrelu(di * (acc.w + h.w) + bb[3]);
        ((float4*)(y2 + (size_t)node * C2))[q] = r;
    }
}

// ---- mean-pool partial sums ----
__global__ __launch_bounds__(256) void k_pool(const float* __restrict__ y2,
                                              const int* __restrict__ batch,
                                              float* __restrict__ gsum,
                                              float* __restrict__ gcnt) {
    __shared__ float ssum[NG * C2];
    __shared__ float scnt[NG];
    for (int i = threadIdx.x; i < NG * C2; i += 256) ssum[i] = 0.f;
    for (int i = threadIdx.x; i < NG; i += 256) scnt[i] = 0.f;
    __syncthreads();
    int node = blockIdx.x * 32 + (threadIdx.x >> 3);
    int col  = threadIdx.x & 7;
    if (node < N_NODES) {
        int g = batch[node];
        float v = y2[(size_t)node * C2 + col];
        atomicAdd(&ssum[g * C2 + col], v);
        if (col == 0) atomicAdd(&scnt[g], 1.f);
    }
    __syncthreads();
    for (int i = threadIdx.x; i < NG * C2; i += 256)
        if (ssum[i] != 0.f) atomicAdd(&gsum[i], ssum[i]);
    for (int i = threadIdx.x; i < NG; i += 256)
        if (scnt[i] != 0.f) atomicAdd(&gcnt[i], scnt[i]);
}

// ---- final MLP ----
__global__ void k_mlp(const float* __restrict__ gsum, const float* __restrict__ gcnt,
                      const float* __restrict__ gfeat,
                      const float* __restrict__ fcW1, const float* __restrict__ fcb1,
                      const float* __restrict__ fcW2, const float* __restrict__ fcb2,
                      float* __restrict__ out) {
    int g = threadIdx.x;
    if (g >= NG) return;
    float z[C2 + GDIM];
    float cnt = fmaxf(gcnt[g], 1.f);
    for (int c = 0; c < C2; ++c) z[c] = gsum[g * C2 + c] / cnt;
    for (int c = 0; c < GDIM; ++c) z[C2 + c] = gfeat[g * GDIM + c];
    float h16[16];
    for (int j = 0; j < 16; ++j) {
        float acc = fcb1[j];
        for (int c = 0; c < C2 + GDIM; ++c) acc += z[c] * fcW1[c * 16 + j];
        h16[j] = lrelu(acc);
    }
    float acc = fcb2[0];
    for (int j = 0; j < 16; ++j) acc += h16[j] * fcW2[j];
    out[g] = lrelu(acc);
}

extern "C" void kernel_launch(void* const* d_in, const int* in_sizes, int n_in,
                              void* d_out, int out_size, void* d_ws, size_t ws_size,
                              hipStream_t stream) {
    const float* x     = (const float*)d_in[0];
    const int*   ei    = (const int*)d_in[1];
    const int*   batch = (const int*)d_in[2];
    const float* gfeat = (const float*)d_in[3];
    const float* W1    = (const float*)d_in[4];
    const float* b1    = (const float*)d_in[5];
    const float* W2    = (const float*)d_in[6];
    const float* b2    = (const float*)d_in[7];
    const float* fcW1  = (const float*)d_in[8];
    const float* fcb1  = (const float*)d_in[9];
    const float* fcW2  = (const float*)d_in[10];
    const float* fcb2  = (const float*)d_in[11];
    const int* src = ei;
    const int* dst = ei + N_EDGES;

    char* ws = (char*)d_ws;
    size_t off = 0;
    auto alloc = [&](size_t bytes) -> void* {
        void* p = ws + off;
        off = (off + bytes + 255) & ~(size_t)255;
        return p;
    };
    int*   deg    = (int*)  alloc((size_t)N_NODES * 4);
    float* dinv   = (float*)alloc((size_t)N_NODES * 4);
    int*   rowptr = (int*)  alloc((size_t)N_NODES * 4);
    int*   bsum   = (int*)  alloc(512 * 4);
    int*   bsumx  = (int*)  alloc(512 * 4);
    int*   rnk    = (int*)  alloc((size_t)N_EDGES * 4);
    int*   eidx   = (int*)  alloc((size_t)N_EDGES * 4);
    float* hs1    = (float*)alloc((size_t)N_NODES * HID * 4);
    float* hs2    = (float*)alloc((size_t)N_NODES * C2 * 4);
    float* y2     = (float*)alloc((size_t)N_NODES * C2 * 4);
    float* gacc   = (float*)alloc((size_t)(NG * C2 + NG) * 4);
    float* gsum   = gacc;
    float* gcnt   = gacc + NG * C2;

    hipMemsetAsync(deg, 0, (size_t)N_NODES * 4, stream);

    k_rank <<<(N_EDGES + 255) / 256, 256, 0, stream>>>(dst, deg, rnk);
    k_dinv <<<NB_SCAN, 256, 0, stream>>>(deg, dinv, gacc);
    k_scan1<<<NB_SCAN, 256, 0, stream>>>(deg, rowptr, bsum);
    k_scan2<<<1, 512, 0, stream>>>(bsum, bsumx);
    k_scan3<<<NB_SCAN, 256, 0, stream>>>(rowptr, bsumx);
    k_place<<<(N_EDGES + 255) / 256, 256, 0, stream>>>(src, dst, rnk, rowptr, eidx);

    k_gemm1<<<N_NODES / 32, 256, 0, stream>>>(x, W1, dinv, hs1);
    k_agg1 <<<N_NODES / 4, 256, 0, stream>>>(rowptr, deg, eidx, hs1, dinv, b1, W2, hs2);
    k_agg2 <<<N_NODES / 4, 256, 0, stream>>>(rowptr, deg, eidx, hs2, dinv, b2, y2);
    k_pool <<<(N_NODES + 31) / 32, 256, 0, stream>>>(y2, batch, gsum, gcnt);
    k_mlp  <<<1, 64, 0, stream>>>(gsum, gcnt, gfeat, fcW1, fcb1, fcW2, fcb2, (float*)d_out);
}